// Round 2
// baseline (761.669 us; speedup 1.0000x reference)
//
#include <hip/hip_runtime.h>
#include <math.h>

#ifndef M_PI
#define M_PI 3.14159265358979323846
#endif

// Problem constants: B=64 images, C=3, H=W=512.
// Loss = mean_b | mean_hf(log10 PSD(gen_b)) - mean_hf(log10 PSD(tgt_b)) |
// hf mask (unshifted freq coords): element counted unless BOTH ky and kx
// are in [0,64) u [448,512).  count = 512^2 - 128^2 = 245760.
//
// ws layout:
//   [0,    2048)  : float2 tw[256]        (W_512^k, k=0..255, fp32 from f64 sincos)
//   [2048, 3072)  : double accum[128]     (sum_gen[64], sum_tgt[64])
//   [4096, ...)   : float2 scratch[chunk][512][512]  (transposed row-FFT output)

__device__ __forceinline__ float2 cmulf(float2 a, float2 b) {
    return make_float2(fmaf(a.x, b.x, -(a.y * b.y)), fmaf(a.x, b.y, a.y * b.x));
}

__device__ __forceinline__ float4 gray01_4(float4 r, float4 g, float4 b) {
    float4 o;
    o.x = (0.299f * r.x + 0.587f * g.x + 0.114f * b.x + 1.0f) * 0.5f;
    o.y = (0.299f * r.y + 0.587f * g.y + 0.114f * b.y + 1.0f) * 0.5f;
    o.z = (0.299f * r.z + 0.587f * g.z + 0.114f * b.z + 1.0f) * 0.5f;
    o.w = (0.299f * r.w + 0.587f * g.w + 0.114f * b.w + 1.0f) * 0.5f;
    return o;
}

__device__ __forceinline__ int brev9(int x) {
    return (int)(__brev((unsigned)x) >> 23);
}

// In-place DIF radix-2 512-pt FFT; one wave (64 lanes) per buffer, 4 butterflies
// per lane per stage. Output at position p equals X[bitrev9(p)].
// Uniform __syncthreads per stage (all waves in the block run this together).
__device__ __forceinline__ void fft512_dif(float2* buf, const float2* tw, int lane) {
#pragma unroll
    for (int s = 0; s < 9; ++s) {
        const int half = 256 >> s;
#pragma unroll
        for (int q = 0; q < 4; ++q) {
            const int i  = lane + (q << 6);
            const int j  = i & (half - 1);
            const int a0 = ((i & ~(half - 1)) << 1) | j;
            float2 u = buf[a0];
            float2 v = buf[a0 + half];
            float2 w = tw[j << s];           // W_512^(j*512/len), len = 2*half
            float2 d = make_float2(u.x - v.x, u.y - v.y);
            buf[a0]        = make_float2(u.x + v.x, u.y + v.y);
            buf[a0 + half] = cmulf(d, w);
        }
        __syncthreads();
    }
}

__global__ void twiddle_kernel(float2* __restrict__ tw) {
    const int k = threadIdx.x;            // 0..255
    const double ang = -2.0 * M_PI * (double)k / 512.0;
    tw[k] = make_float2((float)cos(ang), (float)sin(ang));
}

// Pass 1: grayscale + pack (gen = re, tgt = im) + row FFT, write transposed.
// Block = 512 threads = 8 waves = 8 consecutive rows of one image.
// Grid = chunk * 64 blocks.  scratch[img][col_pos][row] (chunk-local img).
__global__ __launch_bounds__(512)
void row_fft_kernel(const float* __restrict__ gen, const float* __restrict__ tgt,
                    const float2* __restrict__ twg, float2* __restrict__ scratch,
                    int b0) {
    __shared__ float2 tw[256];
    __shared__ float2 data[8 * 514];      // per-wave stride 514 (pad: transpose-read banks)
    const int tid  = threadIdx.x;
    const int wave = tid >> 6, lane = tid & 63;
    const int img  = blockIdx.x >> 6;     // chunk-local image
    const int rg   = blockIdx.x & 63;
    const int b    = b0 + img;            // global image
    const int r0   = rg << 3;
    const int r    = r0 + wave;

    if (tid < 256) tw[tid] = twg[tid];

    const size_t rowoff = ((size_t)b * 3 * 512 + r) * 512;
    const float* gR = gen + rowoff;
    const float* gG = gR + 512 * 512;
    const float* gB = gG + 512 * 512;
    const float* tR = tgt + rowoff;
    const float* tG = tR + 512 * 512;
    const float* tB = tG + 512 * 512;

    float2* buf = data + wave * 514;
#pragma unroll
    for (int q = 0; q < 2; ++q) {
        const int c4 = (lane + (q << 6)) << 2;   // 4-pixel groups
        float4 rr = *(const float4*)(gR + c4);
        float4 gg = *(const float4*)(gG + c4);
        float4 bb = *(const float4*)(gB + c4);
        float4 Gv = gray01_4(rr, gg, bb);
        rr = *(const float4*)(tR + c4);
        gg = *(const float4*)(tG + c4);
        bb = *(const float4*)(tB + c4);
        float4 Tv = gray01_4(rr, gg, bb);
        float4* dst = (float4*)(buf + c4);       // wave*514 even -> 16B aligned
        dst[0] = make_float4(Gv.x, Tv.x, Gv.y, Tv.y);
        dst[1] = make_float4(Gv.z, Tv.z, Gv.w, Tv.w);
    }
    __syncthreads();

    fft512_dif(buf, tw, lane);   // ends with __syncthreads

    // Transposed write: scratch[img][c][r0+j] = row-FFT(row r0+j) at position c.
    const size_t obase = (size_t)img << 18;       // img * 512*512
    const int r0j = r0;
#pragma unroll
    for (int it = 0; it < 8; ++it) {
        const int e = tid + (it << 9);            // 0..4095
        const int c = e >> 3, j = e & 7;
        scratch[obase + ((size_t)c << 9) + r0j + j] = data[j * 514 + c];
    }
}

// Pass 2: column FFT + Hermitian separation + masked log10-PSD reduction.
// Block = 128 threads = 2 waves; wave w handles one column of a conjugate
// kx-pair. pairIdx 0 -> kx {0,256} (self-paired); pairIdx t>=1 -> kx {t,512-t}.
// Grid = chunk * 256 blocks.
__global__ __launch_bounds__(128)
void col_fft_reduce_kernel(const float2* __restrict__ scratch,
                           const float2* __restrict__ twg,
                           double* __restrict__ accum, int b0) {
    __shared__ float2 tw[256];
    __shared__ float2 data[2 * 512];
    const int tid = threadIdx.x, wave = tid >> 6, lane = tid & 63;
    const int img = blockIdx.x >> 8;
    const int t   = blockIdx.x & 255;
    const int b   = b0 + img;
    const int kx  = (t == 0) ? (wave << 8) : (wave ? 512 - t : t);
    const int c   = brev9(kx);                 // column position holding this kx
    float2* buf = data + (wave << 9);

    // BUGFIX (R1 NaN): block has 128 threads; must load all 256 twiddles.
    // Previously only tw[0..127] were initialized -> garbage twiddles ->
    // inf psd -> inf accum -> |inf - inf| = NaN.
    for (int i = tid; i < 256; i += 128) tw[i] = twg[i];

    const float2* src = scratch + ((size_t)img << 18) + ((size_t)c << 9);
#pragma unroll
    for (int q = 0; q < 8; ++q) {
        const int e = lane + (q << 6);
        buf[e] = src[e];
    }
    __syncthreads();

    fft512_dif(buf, tw, lane);   // ends with __syncthreads

    const bool selfp = (kx == 0) || (kx == 256);
    const float2* pbuf = selfp ? buf : (data + ((1 - wave) << 9));
    const bool kxin = (kx < 64) || (kx >= 448);

    double sg = 0.0, st = 0.0;
#pragma unroll
    for (int q = 0; q < 8; ++q) {
        const int m  = lane + (q << 6);
        const int ky = brev9(m);
        if (kxin && (ky < 64 || ky >= 448)) continue;   // masked-out low-freq box
        const float2 F1 = buf[m];
        const int m2 = brev9((512 - ky) & 511);
        const float2 F2 = pbuf[m2];                      // Z[-ky][-kx]
        // A = (F1 + conj(F2))/2  (gen spectrum)
        const float ar = 0.5f * (F1.x + F2.x);
        const float ai = 0.5f * (F1.y - F2.y);
        // B = (F1 - conj(F2))/(2i) (tgt spectrum): (x+iy)/(2i) = (y/2, -x/2)
        const float br = 0.5f * (F1.y + F2.y);
        const float bi = 0.5f * (F2.x - F1.x);
        const float pg = fmaf(ar, ar, ai * ai) + 1e-10f;
        const float pt = fmaf(br, br, bi * bi) + 1e-10f;
        sg += (double)log10f(pg);
        st += (double)log10f(pt);
    }
#pragma unroll
    for (int off = 32; off; off >>= 1) {
        sg += __shfl_down(sg, off);
        st += __shfl_down(st, off);
    }
    if (lane == 0) {
        atomicAdd(&accum[b], sg);
        atomicAdd(&accum[64 + b], st);
    }
}

__global__ void finalize_kernel(const double* __restrict__ accum,
                                float* __restrict__ out) {
    const int lane = threadIdx.x;   // 64 threads
    double d = fabs(accum[lane] - accum[64 + lane]) * (1.0 / 245760.0);
#pragma unroll
    for (int off = 32; off; off >>= 1) d += __shfl_down(d, off);
    if (lane == 0) out[0] = (float)(d * (1.0 / 64.0));   // WEIGHT = 1.0
}

extern "C" void kernel_launch(void* const* d_in, const int* in_sizes, int n_in,
                              void* d_out, int out_size, void* d_ws, size_t ws_size,
                              hipStream_t stream) {
    (void)in_sizes; (void)n_in; (void)out_size;
    const float* gen = (const float*)d_in[0];
    const float* tgt = (const float*)d_in[1];
    float*  out     = (float*)d_out;
    float2* tw      = (float2*)d_ws;
    double* accum   = (double*)((char*)d_ws + 2048);
    float2* scratch = (float2*)((char*)d_ws + 4096);

    // Chunk images so scratch fits ws (and stays L3-resident). 16 imgs = 32 MB.
    const size_t per_img = (size_t)512 * 512 * sizeof(float2);
    const size_t avail = (ws_size > 4096) ? (ws_size - 4096) : 0;
    int chunk = 16;
    while (chunk > 1 && (size_t)chunk * per_img > avail) chunk >>= 1;

    hipMemsetAsync(accum, 0, 128 * sizeof(double), stream);
    twiddle_kernel<<<1, 256, 0, stream>>>(tw);
    for (int b0 = 0; b0 < 64; b0 += chunk) {
        row_fft_kernel<<<dim3(chunk * 64), dim3(512), 0, stream>>>(gen, tgt, tw, scratch, b0);
        col_fft_reduce_kernel<<<dim3(chunk * 256), dim3(128), 0, stream>>>(scratch, tw, accum, b0);
    }
    finalize_kernel<<<1, 64, 0, stream>>>(accum, out);
}

// Round 4
// 755.211 us; speedup vs baseline: 1.0086x; 1.0086x over previous
//
#include <hip/hip_runtime.h>
#include <math.h>

#ifndef M_PI
#define M_PI 3.14159265358979323846
#endif

// B=64, C=3, H=W=512.
// Loss = mean_b | mean_hf(log10 PSD(gen_b)) - mean_hf(log10 PSD(tgt_b)) |
// hf region (unshifted freq): element EXCLUDED iff ky and kx both in [0,64)u[448,512).
// count = 512^2 - 128^2 = 245760.
//
// FFT design: 512 = 8*8*8 Cooley-Tukey, per-wave, 8 complex regs/lane.
//   X[c + 8d + 64e], c,d,e in [0,8):
//   phase1 (lane m): y_c[m]   = W_512^{mc} * DFT8_a( x[64a+m] )
//   phase2 (lane 8c+p): z_cd[p] = W_64^{pd}  * DFT8_b( y_c[8b+p] )
//   phase3 (lane 8c+d): X[c+8d+64e] = DFT8_p( z_cd[p] )
// Two LDS transposes, 4 barriers inside + 1 in caller.
// T1 swizzle: rotation (m + 2c) mod 64 (bijective, bank floor both sides).
// T2 swizzle: (8d + (p^d) + 2c) mod 64 — XOR, bijective, bank floor both sides.
//   (R3 bug: (p + 9d + 2c) mod 64 was NOT bijective — (p,7) collided with (p-1,0).)
//
// ws layout: [0,2048) tw[256]=W_512^k ; [2048,3072) double accum[128] ; [4096,..) scratch.
// scratch column index "col" encodes kx: kx(col) = ((col>>3)&7) + 8*(col&7) + 64*(col>>6)
//                                        col(kx) = 64*(kx>>6) + 8*(kx&7) + ((kx>>3)&7)

__device__ __forceinline__ float2 cmulf(float2 a, float2 b) {
    return make_float2(fmaf(a.x, b.x, -(a.y * b.y)), fmaf(a.x, b.y, a.y * b.x));
}
__device__ __forceinline__ float2 caddf(float2 a, float2 b){ return make_float2(a.x+b.x, a.y+b.y); }
__device__ __forceinline__ float2 csubf(float2 a, float2 b){ return make_float2(a.x-b.x, a.y-b.y); }

// natural-order 8-point DFT: v[k] <- sum_a v[a] W_8^{ak}  (verified vs X[k]=W_8^k by hand)
__device__ __forceinline__ void dft8(float2 v[8]) {
    const float S = 0.70710678118654752440f;
    float2 a0=caddf(v[0],v[4]), a1=caddf(v[1],v[5]), a2=caddf(v[2],v[6]), a3=caddf(v[3],v[7]);
    float2 b0=csubf(v[0],v[4]);
    float2 t1=csubf(v[1],v[5]);
    float2 t2=csubf(v[2],v[6]);
    float2 t3=csubf(v[3],v[7]);
    float2 b1=make_float2(S*(t1.x+t1.y), S*(t1.y-t1.x));   // *(S,-S) = W8^1
    float2 b2=make_float2(t2.y, -t2.x);                    // *(-i)   = W8^2
    float2 b3=make_float2(S*(t3.y-t3.x), -S*(t3.x+t3.y));  // *(-S,-S)= W8^3
    float2 c0=caddf(a0,a2), c1=caddf(a1,a3), c2=csubf(a0,a2);
    float2 u3=csubf(a1,a3); float2 c3=make_float2(u3.y,-u3.x);
    float2 d0=caddf(b0,b2), d1=caddf(b1,b3), d2=csubf(b0,b2);
    float2 w3=csubf(b1,b3); float2 d3=make_float2(w3.y,-w3.x);
    v[0]=caddf(c0,c1); v[4]=csubf(c0,c1);
    v[2]=caddf(c2,c3); v[6]=csubf(c2,c3);
    v[1]=caddf(d0,d1); v[5]=csubf(d0,d1);
    v[3]=caddf(d2,d3); v[7]=csubf(d2,d3);
}

// v[c] *= w^c, c=1..7 (chained; <=7 cmul error ~4e-7, averages out in the loss)
__device__ __forceinline__ void twchain(float2 v[8], float2 w) {
    float2 t = w;
#pragma unroll
    for (int c = 1; c < 8; ++c) {
        v[c] = cmulf(v[c], t);
        if (c < 7) t = cmulf(t, w);
    }
}

// Per-wave 512-pt FFT. In: v[a] = x[64a + lane]. Out: lane L, reg e = X[(L>>3) + 8*(L&7) + 64e].
// W = this wave's private 512-float2 LDS region. 4 uniform __syncthreads inside.
__device__ __forceinline__ void fft512_reg(float2 v[8], float2* __restrict__ W,
                                           const float2* __restrict__ twg, int lane) {
    dft8(v);
    twchain(v, twg[lane]);                                   // W_512^m, m = lane
    // T1 write: slot(c,m) = 64c + ((m + 2c)&63)  -> rotation: bijective, bank floor
#pragma unroll
    for (int c = 0; c < 8; ++c) W[(c<<6) + ((lane + 2*c)&63)] = v[c];
    __syncthreads();
    {   // T1 read: lane (c,p) takes m = 8b+p
        const int c = lane>>3, p = lane&7, base = c<<6, off = p + 2*c;
#pragma unroll
        for (int bb = 0; bb < 8; ++bb) v[bb] = W[base + (((bb<<3) + off)&63)];
    }
    __syncthreads();
    dft8(v);
    twchain(v, twg[(lane&7)<<3]);                            // W_64^p = W_512^{8p}
    {   // T2 write: slot(c,p,d) at 64c + ((8d + (p^d) + 2c)&63)  (XOR: bijective)
        const int c = lane>>3, p = lane&7, base = c<<6, r2 = 2*c;
#pragma unroll
        for (int d = 0; d < 8; ++d) W[base + (((d<<3) + (p^d) + r2)&63)] = v[d];
    }
    __syncthreads();
    {   // T2 read: lane (c,d) takes p = 0..7
        const int c = lane>>3, d = lane&7, base = c<<6, off = (d<<3) + 2*c;
#pragma unroll
        for (int p = 0; p < 8; ++p) v[p] = W[base + ((off + (p^d))&63)];
    }
    __syncthreads();
    dft8(v);
}

__global__ void twiddle_kernel(float2* __restrict__ tw) {
    const int k = threadIdx.x;            // 0..255
    const double ang = -2.0 * M_PI * (double)k / 512.0;
    tw[k] = make_float2((float)cos(ang), (float)sin(ang));
}

// Pass 1: grayscale + pack (gen=re, tgt=im) + row FFT; write transposed scratch[img][col][r].
// Block = 512 thr = 8 waves = 8 rows. Grid = chunk*64.
__global__ __launch_bounds__(512)
void row_fft_kernel(const float* __restrict__ gen, const float* __restrict__ tgt,
                    const float2* __restrict__ twg, float2* __restrict__ scratch,
                    int b0) {
    __shared__ float2 SBUF[8 * 512];      // 32 KB: per-wave FFT region, then reused for out-staging
    const int tid = threadIdx.x, wave = tid>>6, lane = tid&63;
    const int img = blockIdx.x>>6, rg = blockIdx.x&63;
    const int b = b0 + img, r = (rg<<3) + wave;

    const size_t rowoff = ((size_t)b * 3 * 512 + r) * 512;
    const float* gR = gen + rowoff; const float* gG = gR + 262144; const float* gB = gG + 262144;
    const float* tR = tgt + rowoff; const float* tG = tR + 262144; const float* tB = tG + 262144;

    float2 v[8];
#pragma unroll
    for (int a = 0; a < 8; ++a) {          // coalesced dword loads, 64 lanes consecutive
        const int idx = (a<<6) + lane;
        const float gg = fmaf(0.299f, gR[idx], fmaf(0.587f, gG[idx], fmaf(0.114f, gB[idx], 1.0f))) * 0.5f;
        const float tt = fmaf(0.299f, tR[idx], fmaf(0.587f, tG[idx], fmaf(0.114f, tB[idx], 1.0f))) * 0.5f;
        v[a] = make_float2(gg, tt);        // (gray01(gen), gray01(tgt))
    }

    float2* W = SBUF + (wave<<9);
    fft512_reg(v, W, twg, lane);

    // out-staging (overlays FFT region; safe: last barrier drained all reads):
    // slot = 512*wave + ((col + 8*wave)&511), col = 64e + lane (col encodes kx, see header)
#pragma unroll
    for (int e = 0; e < 8; ++e) {
        const int col = (e<<6) + lane;
        W[(col + (wave<<3)) & 511] = v[e];
    }
    __syncthreads();

    const size_t obase = (size_t)img << 18;   // img * 512*512
    const int r0 = rg<<3;
#pragma unroll
    for (int it = 0; it < 8; ++it) {          // 64B-contiguous global segments
        const int col = (tid>>3) + (it<<6);
        const int j = tid&7;
        scratch[obase + ((size_t)col<<9) + r0 + j] = SBUF[(j<<9) + ((col + (j<<3)) & 511)];
    }
}

// Pass 2: column FFT + Hermitian split + masked log10-PSD reduce.
// Block = 128 thr = 2 waves = conjugate kx pair. Grid = chunk*256.
__global__ __launch_bounds__(128)
void col_fft_reduce_kernel(const float2* __restrict__ scratch,
                           const float2* __restrict__ twg,
                           double* __restrict__ accum, int b0) {
    __shared__ float2 SBUF[2 * 512];      // 8 KB
    const int tid = threadIdx.x, wave = tid>>6, lane = tid&63;
    const int img = blockIdx.x>>8, t = blockIdx.x&255;
    const int b = b0 + img;
    const int kx = (t==0) ? (wave<<8) : (wave ? 512-t : t);
    const int col = ((kx>>6)<<6) + ((kx&7)<<3) + ((kx>>3)&7);   // col(kx)
    float2* W = SBUF + (wave<<9);

    const float2* src = scratch + ((size_t)img<<18) + ((size_t)col<<9);
    float2 v[8];
#pragma unroll
    for (int a = 0; a < 8; ++a) v[a] = src[(a<<6) + lane];      // coalesced dwordx2

    fft512_reg(v, W, twg, lane);

    // publish own spectrum in natural-ky order (uniform 4 lanes/bank-pair = floor)
    const int cc = lane>>3, dd = lane&7;
#pragma unroll
    for (int e = 0; e < 8; ++e) W[cc + (dd<<3) + (e<<6)] = v[e];
    __syncthreads();

    const float2* pbuf = (t==0) ? W : (SBUF + ((1-wave)<<9));   // kx=0/256 self-paired
    const bool kxin = (kx < 64) || (kx >= 448);

    double sg = 0.0, st = 0.0;
#pragma unroll
    for (int e = 0; e < 8; ++e) {
        const int ky = cc + (dd<<3) + (e<<6);
        if (kxin && ((ky < 64) || (ky >= 448))) continue;       // excluded low-freq box
        const float2 F1 = v[e];
        const float2 F2 = pbuf[(512 - ky) & 511];               // Z[-ky][-kx]
        const float ar = 0.5f*(F1.x + F2.x), ai = 0.5f*(F1.y - F2.y);   // gen spectrum
        const float br = 0.5f*(F1.y + F2.y), bi = 0.5f*(F2.x - F1.x);   // tgt spectrum
        const float pg = fmaf(ar, ar, ai*ai) + 1e-10f;
        const float pt = fmaf(br, br, bi*bi) + 1e-10f;
        sg += (double)log10f(pg);
        st += (double)log10f(pt);
    }
#pragma unroll
    for (int off = 32; off; off >>= 1) {
        sg += __shfl_down(sg, off);
        st += __shfl_down(st, off);
    }
    if (lane == 0) {
        atomicAdd(&accum[b], sg);
        atomicAdd(&accum[64 + b], st);
    }
}

__global__ void finalize_kernel(const double* __restrict__ accum,
                                float* __restrict__ out) {
    const int lane = threadIdx.x;   // 64
    double d = fabs(accum[lane] - accum[64 + lane]) * (1.0 / 245760.0);
#pragma unroll
    for (int off = 32; off; off >>= 1) d += __shfl_down(d, off);
    if (lane == 0) out[0] = (float)(d * (1.0 / 64.0));   // WEIGHT = 1.0
}

extern "C" void kernel_launch(void* const* d_in, const int* in_sizes, int n_in,
                              void* d_out, int out_size, void* d_ws, size_t ws_size,
                              hipStream_t stream) {
    (void)in_sizes; (void)n_in; (void)out_size;
    const float* gen = (const float*)d_in[0];
    const float* tgt = (const float*)d_in[1];
    float*  out     = (float*)d_out;
    float2* tw      = (float2*)d_ws;
    double* accum   = (double*)((char*)d_ws + 2048);
    float2* scratch = (float2*)((char*)d_ws + 4096);

    const size_t per_img = (size_t)512 * 512 * sizeof(float2);
    const size_t avail = (ws_size > 4096) ? (ws_size - 4096) : 0;
    int chunk = 16;                      // 32 MB scratch: L3-resident
    while (chunk > 1 && (size_t)chunk * per_img > avail) chunk >>= 1;

    hipMemsetAsync(accum, 0, 128 * sizeof(double), stream);
    twiddle_kernel<<<1, 256, 0, stream>>>(tw);
    for (int b0 = 0; b0 < 64; b0 += chunk) {
        row_fft_kernel<<<dim3(chunk * 64), dim3(512), 0, stream>>>(gen, tgt, tw, scratch, b0);
        col_fft_reduce_kernel<<<dim3(chunk * 256), dim3(128), 0, stream>>>(scratch, tw, accum, b0);
    }
    finalize_kernel<<<1, 64, 0, stream>>>(accum, out);
}